// Round 2
// baseline (485.888 us; speedup 1.0000x reference)
//
#include <hip/hip_runtime.h>
#include <hip/hip_bf16.h>

// Problem constants (Qwen3-Next linear attention defaults)
#define S_LEN   256
#define HID     2048
#define NVH     32
#define DKD     128
#define DVD     128
#define KEYDIM  512
#define VALDIM  4096
#define CONVDIM 5120
#define QKVZ_N  9216
#define EPS_F   1e-6f

typedef __attribute__((ext_vector_type(8))) short bf16x8;
typedef __attribute__((ext_vector_type(4))) float f32x4;

__device__ __forceinline__ float bf2f(unsigned short u) {
    union { unsigned int i; float f; } v; v.i = ((unsigned int)u) << 16; return v.f;
}
__device__ __forceinline__ unsigned short f2bf(float f) {
    union { float f; unsigned int i; } v; v.f = f;
    unsigned int x = v.i;
    return (unsigned short)((x + 0x7FFFu + ((x >> 16) & 1u)) >> 16); // RNE
}

// load 8 contiguous fp32 from global, convert RNE -> 8 bf16, store 16B to LDS
__device__ __forceinline__ void cvt8_store(const float* __restrict__ g,
                                           unsigned short* __restrict__ lds) {
    float4 f0 = *(const float4*)g;
    float4 f1 = *(const float4*)(g + 4);
    unsigned short t[8] = {f2bf(f0.x), f2bf(f0.y), f2bf(f0.z), f2bf(f0.w),
                           f2bf(f1.x), f2bf(f1.y), f2bf(f1.z), f2bf(f1.w)};
    *(uint4*)lds = *(uint4*)t;
}

// ---------------------------------------------------------------------------
// MFMA GEMM: C[M,N] = A[M,K] @ B[N,K]^T. A is fp32 or bf16 (A_F32), B fp32 or
// bf16 (B_F32); converted to bf16 during LDS staging. C fp32.
// Block = 256 threads = 4 waves (2x2), tile 128x128, BK=32.
// mfma_f32_16x16x32_bf16 layouts (HW-verified, guide §3):
//   A-frag: A[m=lane&15][k=(lane>>4)*8+j]   B-frag: B[n=lane&15][k=(lane>>4)*8+j]
//   C/D:    row=(lane>>4)*4+reg, col=lane&15
// ---------------------------------------------------------------------------
template<bool A_F32, bool B_F32>
__global__ __launch_bounds__(256)
void mfma_gemm(const void* __restrict__ A, const void* __restrict__ B,
               float* __restrict__ C, int N, int K) {
    __shared__ __align__(16) unsigned short As[128][40]; // +8 bf16 pad per row
    __shared__ __align__(16) unsigned short Bs[128][40];

    const int tid  = threadIdx.x;
    const int lane = tid & 63, wave = tid >> 6;
    const int wm = wave >> 1, wn = wave & 1;
    const int quad = lane >> 4, l16 = lane & 15;
    const int m0 = blockIdx.y * 128, n0 = blockIdx.x * 128;

    f32x4 acc[4][4];
#pragma unroll
    for (int i = 0; i < 4; i++)
#pragma unroll
        for (int j = 0; j < 4; j++) acc[i][j] = (f32x4){0.f, 0.f, 0.f, 0.f};

    const int tr = tid >> 2;          // 0..63
    const int tc = (tid & 3) << 3;    // 0,8,16,24 (elements)

    for (int k0 = 0; k0 < K; k0 += 32) {
#pragma unroll
        for (int p = 0; p < 2; p++) {
            const int row = p * 64 + tr;
            if constexpr (A_F32)
                cvt8_store((const float*)A + (size_t)(m0 + row) * K + k0 + tc, &As[row][tc]);
            else
                *(uint4*)(&As[row][tc]) =
                    *(const uint4*)((const unsigned short*)A + (size_t)(m0 + row) * K + k0 + tc);
            if constexpr (B_F32)
                cvt8_store((const float*)B + (size_t)(n0 + row) * K + k0 + tc, &Bs[row][tc]);
            else
                *(uint4*)(&Bs[row][tc]) =
                    *(const uint4*)((const unsigned short*)B + (size_t)(n0 + row) * K + k0 + tc);
        }
        __syncthreads();
        bf16x8 af[4], bfr[4];
#pragma unroll
        for (int t = 0; t < 4; t++) {
            af[t]  = *(const bf16x8*)(&As[wm * 64 + t * 16 + l16][quad * 8]);
            bfr[t] = *(const bf16x8*)(&Bs[wn * 64 + t * 16 + l16][quad * 8]);
        }
#pragma unroll
        for (int i = 0; i < 4; i++)
#pragma unroll
            for (int j = 0; j < 4; j++)
                acc[i][j] = __builtin_amdgcn_mfma_f32_16x16x32_bf16(af[i], bfr[j], acc[i][j], 0, 0, 0);
        __syncthreads();
    }

#pragma unroll
    for (int i = 0; i < 4; i++)
#pragma unroll
        for (int j = 0; j < 4; j++)
#pragma unroll
            for (int r = 0; r < 4; r++) {
                int row = m0 + wm * 64 + i * 16 + quad * 4 + r;
                int col = n0 + wn * 64 + j * 16 + l16;
                C[(size_t)row * N + col] = acc[i][j][r];
            }
}

// ba = hidden @ w_ba^T : [256,64]. Tiny GEMM; 256 blocks x 64 threads.
__global__ void ba_proj(const float* __restrict__ hs,
                        const float* __restrict__ w_ba,
                        float* __restrict__ ba) {
    int s = blockIdx.x, n = threadIdx.x;
    const float* x = hs + (size_t)s * HID;
    const float* w = w_ba + (size_t)n * HID;
    float acc = 0.f;
    for (int k = 0; k < HID; k += 4) {
        float4 xv = *(const float4*)(x + k);
        float4 wv = *(const float4*)(w + k);
        acc += xv.x * wv.x + xv.y * wv.y + xv.z * wv.z + xv.w * wv.w;
    }
    ba[s * 64 + n] = acc;
}

// causal depthwise conv (K=4) + silu over qkv channels (cols 0..5119 of qkvz)
__global__ void conv_silu(const float* __restrict__ qkvz,
                          const float* __restrict__ conv_w,
                          float* __restrict__ out) {
    int idx = blockIdx.x * blockDim.x + threadIdx.x;
    if (idx >= S_LEN * CONVDIM) return;
    int s = idx / CONVDIM, c = idx % CONVDIM;
    float acc = 0.f;
#pragma unroll
    for (int j = 0; j < 4; j++) {
        int t = s - 3 + j;
        if (t >= 0) acc += qkvz[(size_t)t * QKVZ_N + c] * conv_w[c * 4 + j];
    }
    out[idx] = acc / (1.f + __expf(-acc)); // silu
}

// scores[n][s][t] = (t<=s) ? (q[s]·k[t]) * DK^-0.5 * sigmoid(beta[t,n]+dt_bias[n]) : 0
__global__ __launch_bounds__(256)
void scores_k(const float* __restrict__ conv, const float* __restrict__ ba,
              const float* __restrict__ dt_bias, float* __restrict__ scores) {
    int n = blockIdx.z;
    int s0 = blockIdx.y * 16, t0 = blockIdx.x * 16;
    __shared__ float Qs[16][132], Ks[16][132];
    int tid = threadIdx.x;
    int qoff = (n >> 3) * DKD;            // repeat_interleave: q/k head = n/8
    int koff = KEYDIM + (n >> 3) * DKD;
    for (int idx = tid; idx < 16 * 128; idx += 256) {
        int i = idx >> 7, d = idx & 127;
        Qs[i][d] = conv[(size_t)(s0 + i) * CONVDIM + qoff + d];
        Ks[i][d] = conv[(size_t)(t0 + i) * CONVDIM + koff + d];
    }
    __syncthreads();
    int tx = tid & 15, ty = tid >> 4;
    int s = s0 + ty, t = t0 + tx;
    float val = 0.f;
    if (t <= s) {
        float dot = 0.f;
        for (int d = 0; d < 128; d++) dot += Qs[ty][d] * Ks[tx][d];
        float b = ba[t * 64 + n] + dt_bias[n];   // beta = ba[..., :32]
        float bg = 1.f / (1.f + __expf(-b));
        val = dot * 0.08838834764831845f * bg;   // DK^-0.5
    }
    scores[((size_t)n * 256 + s) * 256 + t] = val;
}

// attn[s][n][d] = sum_t scores[n][s][t] * v[t][n][d]
__global__ __launch_bounds__(256)
void attn_v(const float* __restrict__ scores, const float* __restrict__ conv,
            float* __restrict__ attn) {
    int n = blockIdx.z, s0 = blockIdx.y * 16, d0 = blockIdx.x * 16;
    int voff = 2 * KEYDIM + n * DVD;
    __shared__ float Ss[16][16], Vs[16][17];
    int tid = threadIdx.x, dx = tid & 15, sy = tid >> 4;
    float acc = 0.f;
    for (int t0 = 0; t0 <= s0; t0 += 16) {
        Ss[sy][dx] = scores[((size_t)n * 256 + s0 + sy) * 256 + t0 + dx];
        Vs[sy][dx] = conv[(size_t)(t0 + sy) * CONVDIM + voff + d0 + dx];
        __syncthreads();
#pragma unroll
        for (int j = 0; j < 16; j++) acc += Ss[sy][j] * Vs[j][dx];
        __syncthreads();
    }
    attn[((size_t)(s0 + sy) * NVH + n) * DVD + d0 + dx] = acc;
}

// gated RMSNorm over DV + silu(z) gate; emit bf16 for the final MFMA GEMM
__global__ __launch_bounds__(128)
void rmsnorm_gate(const float* __restrict__ attn, const float* __restrict__ qkvz,
                  const float* __restrict__ norm_w,
                  unsigned short* __restrict__ normed) {
    int s = blockIdx.x >> 5, n = blockIdx.x & 31;
    int d = threadIdx.x;
    float x = attn[((size_t)s * NVH + n) * DVD + d];
    float sq = x * x;
#pragma unroll
    for (int off = 32; off > 0; off >>= 1) sq += __shfl_down(sq, off, 64);
    __shared__ float parts[2];
    if ((d & 63) == 0) parts[d >> 6] = sq;
    __syncthreads();
    float ms = (parts[0] + parts[1]) * (1.f / 128.f);
    float inv = rsqrtf(ms + EPS_F);
    float z = qkvz[(size_t)s * QKVZ_N + CONVDIM + n * DVD + d];
    float sz = z / (1.f + __expf(-z));
    float v = x * inv * norm_w[d] * sz;
    normed[((size_t)s * NVH + n) * DVD + d] = f2bf(v);
}

extern "C" void kernel_launch(void* const* d_in, const int* in_sizes, int n_in,
                              void* d_out, int out_size, void* d_ws, size_t ws_size,
                              hipStream_t stream) {
    const float* hs      = (const float*)d_in[0];
    const float* w_qkvz  = (const float*)d_in[1];
    const float* w_ba    = (const float*)d_in[2];
    const float* w_out   = (const float*)d_in[3];
    const float* conv_w  = (const float*)d_in[4];
    const float* dt_bias = (const float*)d_in[5];
    // d_in[6] = A_log (dead code in reference)
    const float* norm_w  = (const float*)d_in[7];

    char* ws = (char*)d_ws;
    float* qkvz   = (float*)ws;          ws += (size_t)S_LEN * QKVZ_N * 4;
    float* ba     = (float*)ws;          ws += (size_t)S_LEN * 64 * 4;
    float* conv   = (float*)ws;          ws += (size_t)S_LEN * CONVDIM * 4;
    float* scores = (float*)ws;          ws += (size_t)NVH * S_LEN * S_LEN * 4;
    float* attn   = (float*)ws;          ws += (size_t)S_LEN * VALDIM * 4;
    unsigned short* normed = (unsigned short*)ws;   // [256,4096] bf16

    // 1) qkvz = X @ Wqkvz^T   (M=256, N=9216, K=2048), fp32 in, fp32 out
    mfma_gemm<true, true><<<dim3(QKVZ_N / 128, 2), 256, 0, stream>>>(hs, w_qkvz, qkvz, QKVZ_N, HID);
    // 2) ba = X @ Wba^T
    ba_proj<<<S_LEN, 64, 0, stream>>>(hs, w_ba, ba);
    // 3) depthwise causal conv + silu
    conv_silu<<<(S_LEN * CONVDIM) / 256, 256, 0, stream>>>(qkvz, conv_w, conv);
    // 4) causal scores with beta folded in
    scores_k<<<dim3(16, 16, NVH), 256, 0, stream>>>(conv, ba, dt_bias, scores);
    // 5) attn = scores @ V
    attn_v<<<dim3(8, 16, NVH), 256, 0, stream>>>(scores, conv, attn);
    // 6) gated RMSNorm -> bf16
    rmsnorm_gate<<<S_LEN * NVH, 128, 0, stream>>>(attn, qkvz, norm_w, normed);
    // 7) out = normed @ Wout^T  (M=256, N=2048, K=4096), A bf16, B fp32 -> fp32 d_out
    mfma_gemm<false, true><<<dim3(HID / 128, 2), 256, 0, stream>>>(normed, w_out, (float*)d_out, HID, VALDIM);
}

// Round 3
// 296.221 us; speedup vs baseline: 1.6403x; 1.6403x over previous
//
#include <hip/hip_runtime.h>
#include <hip/hip_bf16.h>

// Problem constants (Qwen3-Next linear attention defaults)
#define S_LEN   256
#define HID     2048
#define NVH     32
#define DKD     128
#define DVD     128
#define KEYDIM  512
#define VALDIM  4096
#define CONVDIM 5120
#define QKVZ_N  9216
#define EPS_F   1e-6f

typedef __attribute__((ext_vector_type(8))) short bf16x8;
typedef __attribute__((ext_vector_type(4))) float f32x4;

__device__ __forceinline__ unsigned short f2bf(float f) {
    union { float f; unsigned int i; } v; v.f = f;
    unsigned int x = v.i;
    return (unsigned short)((x + 0x7FFFu + ((x >> 16) & 1u)) >> 16); // RNE
}
// packed fp32x2 -> bf16x2 (v_cvt_pk_bf16_f32 on gfx950)
__device__ __forceinline__ unsigned int pk2(float x, float y) {
    union { __hip_bfloat162 h; unsigned int u; } c;
    c.h = __float22bfloat162_rn(float2{x, y});
    return c.u;
}
__device__ __forceinline__ float4 asf4(uint4 u) {
    union { uint4 u; float4 f; } c; c.u = u; return c.f;
}
__device__ __forceinline__ uint4 cvt8_pack(float4 a, float4 b) {
    uint4 r;
    r.x = pk2(a.x, a.y); r.y = pk2(a.z, a.w);
    r.z = pk2(b.x, b.y); r.w = pk2(b.z, b.w);
    return r;
}

// ---------------------------------------------------------------------------
// Split-K MFMA GEMM: Cpart[z] = A[M,K-chunk] @ B[N,K-chunk]^T.
// A fp32 (A_F32) or bf16; B fp32 (converted to bf16 in staging). M fixed 256.
// Block = 256 thr = 4 waves (2x2), tile 128x128, BK=64, register prefetch.
// mfma_f32_16x16x32_bf16 layouts (HW-verified):
//   A-frag: A[m=lane&15][k=(lane>>4)*8+j]; C/D: row=(lane>>4)*4+reg, col=lane&15
// ---------------------------------------------------------------------------
template<bool A_F32>
__global__ __launch_bounds__(256, 2)
void gemm_tile(const void* __restrict__ Ap, const float* __restrict__ B,
               float* __restrict__ Cpart, int N, int K, int kc) {
    __shared__ __align__(16) unsigned short As[128][72]; // 144B row stride: 16B-aligned
    __shared__ __align__(16) unsigned short Bs[128][72];

    const int tid  = threadIdx.x;
    const int lane = tid & 63, wave = tid >> 6;
    const int wm = wave >> 1, wn = wave & 1;
    const int quad = lane >> 4, l16 = lane & 15;
    const int m0 = blockIdx.y * 128, n0 = blockIdx.x * 128;
    const int kbeg = blockIdx.z * kc;
    const int niter = kc >> 6;           // BK = 64

    const int lc = (tid & 7) << 3;       // col element 0,8,...,56
    const int lr = tid >> 3;             // row 0..31

    f32x4 acc[4][4];
#pragma unroll
    for (int i = 0; i < 4; i++)
#pragma unroll
        for (int j = 0; j < 4; j++) acc[i][j] = (f32x4){0.f, 0.f, 0.f, 0.f};

    uint4 qa[8], qb[8];  // prefetch regs (A: f32 uses 8, bf16 uses 4)

    auto ld_tiles = [&](int kk) {
        if constexpr (A_F32) {
            const float* a = (const float*)Ap + (size_t)(m0 + lr) * K + kk + lc;
#pragma unroll
            for (int i = 0; i < 4; i++) {
                qa[2 * i]     = *(const uint4*)(a + (size_t)(32 * i) * K);
                qa[2 * i + 1] = *(const uint4*)(a + (size_t)(32 * i) * K + 4);
            }
        } else {
            const unsigned short* a = (const unsigned short*)Ap + (size_t)(m0 + lr) * K + kk + lc;
#pragma unroll
            for (int i = 0; i < 4; i++)
                qa[i] = *(const uint4*)(a + (size_t)(32 * i) * K);
        }
        const float* b = B + (size_t)(n0 + lr) * K + kk + lc;
#pragma unroll
        for (int i = 0; i < 4; i++) {
            qb[2 * i]     = *(const uint4*)(b + (size_t)(32 * i) * K);
            qb[2 * i + 1] = *(const uint4*)(b + (size_t)(32 * i) * K + 4);
        }
    };
    auto st_tiles = [&]() {
#pragma unroll
        for (int i = 0; i < 4; i++) {
            if constexpr (A_F32)
                *(uint4*)(&As[lr + 32 * i][lc]) = cvt8_pack(asf4(qa[2 * i]), asf4(qa[2 * i + 1]));
            else
                *(uint4*)(&As[lr + 32 * i][lc]) = qa[i];
            *(uint4*)(&Bs[lr + 32 * i][lc]) = cvt8_pack(asf4(qb[2 * i]), asf4(qb[2 * i + 1]));
        }
    };

    ld_tiles(kbeg);
    st_tiles();
    __syncthreads();

    for (int it = 0; it < niter; ++it) {
        if (it + 1 < niter) ld_tiles(kbeg + (it + 1) * 64);  // in flight during MFMA

        bf16x8 af[2][4], bfr[2][4];
#pragma unroll
        for (int t = 0; t < 4; t++) {
#pragma unroll
            for (int ks = 0; ks < 2; ks++) {
                af[ks][t]  = *(const bf16x8*)(&As[wm * 64 + t * 16 + l16][ks * 32 + quad * 8]);
                bfr[ks][t] = *(const bf16x8*)(&Bs[wn * 64 + t * 16 + l16][ks * 32 + quad * 8]);
            }
        }
#pragma unroll
        for (int ks = 0; ks < 2; ks++)
#pragma unroll
            for (int i = 0; i < 4; i++)
#pragma unroll
                for (int j = 0; j < 4; j++)
                    acc[i][j] = __builtin_amdgcn_mfma_f32_16x16x32_bf16(af[ks][i], bfr[ks][j], acc[i][j], 0, 0, 0);

        if (it + 1 < niter) {
            __syncthreads();
            st_tiles();
            __syncthreads();
        }
    }

    float* C = Cpart + (size_t)blockIdx.z * 256 * N;
#pragma unroll
    for (int i = 0; i < 4; i++)
#pragma unroll
        for (int j = 0; j < 4; j++)
#pragma unroll
            for (int r = 0; r < 4; r++) {
                int row = m0 + wm * 64 + i * 16 + quad * 4 + r;
                int col = n0 + wn * 64 + j * 16 + l16;
                C[(size_t)row * N + col] = acc[i][j][r];
            }
}

// sum P split-K partials (each n floats apart), float4-vectorized
template<int P>
__global__ void reduce_sum(const float* __restrict__ part, float* __restrict__ out, int n) {
    int i = (blockIdx.x * 256 + threadIdx.x) * 4;
    if (i >= n) return;
    float4 s = *(const float4*)(part + i);
#pragma unroll
    for (int p = 1; p < P; p++) {
        float4 v = *(const float4*)(part + (size_t)p * n + i);
        s.x += v.x; s.y += v.y; s.z += v.z; s.w += v.w;
    }
    *(float4*)(out + i) = s;
}

// ba = hidden @ w_ba^T : [256,64]
__global__ void ba_proj(const float* __restrict__ hs,
                        const float* __restrict__ w_ba,
                        float* __restrict__ ba) {
    int s = blockIdx.x, n = threadIdx.x;
    const float* x = hs + (size_t)s * HID;
    const float* w = w_ba + (size_t)n * HID;
    float acc = 0.f;
    for (int k = 0; k < HID; k += 4) {
        float4 xv = *(const float4*)(x + k);
        float4 wv = *(const float4*)(w + k);
        acc += xv.x * wv.x + xv.y * wv.y + xv.z * wv.z + xv.w * wv.w;
    }
    ba[s * 64 + n] = acc;
}

// causal depthwise conv (K=4) + silu over qkv channels (cols 0..5119 of qkvz)
__global__ void conv_silu(const float* __restrict__ qkvz,
                          const float* __restrict__ conv_w,
                          float* __restrict__ out) {
    int idx = blockIdx.x * blockDim.x + threadIdx.x;
    if (idx >= S_LEN * CONVDIM) return;
    int s = idx / CONVDIM, c = idx % CONVDIM;
    float acc = 0.f;
#pragma unroll
    for (int j = 0; j < 4; j++) {
        int t = s - 3 + j;
        if (t >= 0) acc += qkvz[(size_t)t * QKVZ_N + c] * conv_w[c * 4 + j];
    }
    out[idx] = acc / (1.f + __expf(-acc)); // silu
}

// scores[n][s][t] = (t<=s) ? (q[s]·k[t]) * DK^-0.5 * sigmoid(beta[t,n]+dt_bias[n]) : 0
// GQA: dot depends only on hk = n>>3 -> compute once, fan out over 8 v-heads.
__global__ __launch_bounds__(256)
void scores_k(const float* __restrict__ conv, const float* __restrict__ ba,
              const float* __restrict__ dt_bias, float* __restrict__ scores) {
    if (blockIdx.x > blockIdx.y) return;          // strictly-upper tiles never read
    int hk = blockIdx.z;                          // 0..3
    int s0 = blockIdx.y * 16, t0 = blockIdx.x * 16;
    __shared__ float Qs[16][132], Ks[16][132];
    int tid = threadIdx.x;
    int qoff = hk * DKD;
    int koff = KEYDIM + hk * DKD;
    for (int idx = tid; idx < 16 * 128; idx += 256) {
        int i = idx >> 7, d = idx & 127;
        Qs[i][d] = conv[(size_t)(s0 + i) * CONVDIM + qoff + d];
        Ks[i][d] = conv[(size_t)(t0 + i) * CONVDIM + koff + d];
    }
    __syncthreads();
    int tx = tid & 15, ty = tid >> 4;
    int s = s0 + ty, t = t0 + tx;
    float dot = 0.f;
    for (int d = 0; d < 128; d++) dot += Qs[ty][d] * Ks[tx][d];
    float base = (t <= s) ? dot * 0.08838834764831845f : 0.f;
#pragma unroll
    for (int v = 0; v < 8; v++) {
        int n = hk * 8 + v;
        float b = ba[t * 64 + n] + dt_bias[n];
        float bg = 1.f / (1.f + __expf(-b));
        scores[((size_t)n * 256 + s) * 256 + t] = base * bg;
    }
}

// attn[s][n][d] = sum_t scores[n][s][t] * v[t][n][d]
__global__ __launch_bounds__(256)
void attn_v(const float* __restrict__ scores, const float* __restrict__ conv,
            float* __restrict__ attn) {
    int n = blockIdx.z, s0 = blockIdx.y * 16, d0 = blockIdx.x * 16;
    int voff = 2 * KEYDIM + n * DVD;
    __shared__ float Ss[16][16], Vs[16][17];
    int tid = threadIdx.x, dx = tid & 15, sy = tid >> 4;
    float acc = 0.f;
    for (int t0 = 0; t0 <= s0; t0 += 16) {
        Ss[sy][dx] = scores[((size_t)n * 256 + s0 + sy) * 256 + t0 + dx];
        Vs[sy][dx] = conv[(size_t)(t0 + sy) * CONVDIM + voff + d0 + dx];
        __syncthreads();
#pragma unroll
        for (int j = 0; j < 16; j++) acc += Ss[sy][j] * Vs[j][dx];
        __syncthreads();
    }
    attn[((size_t)(s0 + sy) * NVH + n) * DVD + d0 + dx] = acc;
}

// gated RMSNorm over DV + silu(z) gate; emit bf16 for the final MFMA GEMM
__global__ __launch_bounds__(128)
void rmsnorm_gate(const float* __restrict__ attn, const float* __restrict__ qkvz,
                  const float* __restrict__ norm_w,
                  unsigned short* __restrict__ normed) {
    int s = blockIdx.x >> 5, n = blockIdx.x & 31;
    int d = threadIdx.x;
    float x = attn[((size_t)s * NVH + n) * DVD + d];
    float sq = x * x;
#pragma unroll
    for (int off = 32; off > 0; off >>= 1) sq += __shfl_down(sq, off, 64);
    __shared__ float parts[2];
    if ((d & 63) == 0) parts[d >> 6] = sq;
    __syncthreads();
    float ms = (parts[0] + parts[1]) * (1.f / 128.f);
    float inv = rsqrtf(ms + EPS_F);
    float z = qkvz[(size_t)s * QKVZ_N + CONVDIM + n * DVD + d];
    float sz = z / (1.f + __expf(-z));
    float v = x * inv * norm_w[d] * sz;
    normed[((size_t)s * NVH + n) * DVD + d] = f2bf(v);
}

extern "C" void kernel_launch(void* const* d_in, const int* in_sizes, int n_in,
                              void* d_out, int out_size, void* d_ws, size_t ws_size,
                              hipStream_t stream) {
    const float* hs      = (const float*)d_in[0];
    const float* w_qkvz  = (const float*)d_in[1];
    const float* w_ba    = (const float*)d_in[2];
    const float* w_out   = (const float*)d_in[3];
    const float* conv_w  = (const float*)d_in[4];
    const float* dt_bias = (const float*)d_in[5];
    // d_in[6] = A_log (dead code in reference)
    const float* norm_w  = (const float*)d_in[7];

    char* ws = (char*)d_ws;
    float* qkvz   = (float*)ws;          ws += (size_t)S_LEN * QKVZ_N * 4;     // 9.44 MB
    float* ba     = (float*)ws;          ws += (size_t)S_LEN * 64 * 4;
    float* conv   = (float*)ws;          ws += (size_t)S_LEN * CONVDIM * 4;    // 5.24 MB
    float* scores = (float*)ws;          ws += (size_t)NVH * S_LEN * S_LEN * 4;// 8.39 MB
    float* attn   = (float*)ws;          ws += (size_t)S_LEN * VALDIM * 4;     // 4.19 MB
    unsigned short* normed = (unsigned short*)ws; ws += (size_t)S_LEN * VALDIM * 2;
    float* scratch = (float*)ws; // split-K partials: max(2x9.44, 8x2.10) = 18.9 MB

    // 1) qkvz partials = X @ Wqkvz^T  (M=256,N=9216,K=2048), split-K=2 -> 288 blocks
    gemm_tile<true><<<dim3(QKVZ_N / 128, 2, 2), 256, 0, stream>>>(hs, w_qkvz, scratch, QKVZ_N, HID, HID / 2);
    // 2) ba = X @ Wba^T
    ba_proj<<<S_LEN, 64, 0, stream>>>(hs, w_ba, ba);
    // 3) reduce split-K -> qkvz
    reduce_sum<2><<<(S_LEN * QKVZ_N) / 1024, 256, 0, stream>>>(scratch, qkvz, S_LEN * QKVZ_N);
    // 4) depthwise causal conv + silu
    conv_silu<<<(S_LEN * CONVDIM) / 256, 256, 0, stream>>>(qkvz, conv_w, conv);
    // 5) causal scores (dot once per k-head, fan out over 8 v-heads)
    scores_k<<<dim3(16, 16, 4), 256, 0, stream>>>(conv, ba, dt_bias, scores);
    // 6) attn = scores @ V
    attn_v<<<dim3(8, 16, NVH), 256, 0, stream>>>(scores, conv, attn);
    // 7) gated RMSNorm -> bf16
    rmsnorm_gate<<<S_LEN * NVH, 128, 0, stream>>>(attn, qkvz, norm_w, normed);
    // 8) out partials = normed @ Wout^T (M=256,N=2048,K=4096), split-K=8 -> 256 blocks
    gemm_tile<false><<<dim3(HID / 128, 2, 8), 256, 0, stream>>>(normed, w_out, scratch, HID, VALDIM, VALDIM / 8);
    // 9) reduce split-K -> d_out (fp32)
    reduce_sum<8><<<(S_LEN * HID) / 1024, 256, 0, stream>>>(scratch, (float*)d_out, S_LEN * HID);
}

// Round 4
// 274.496 us; speedup vs baseline: 1.7701x; 1.0791x over previous
//
#include <hip/hip_runtime.h>
#include <hip/hip_bf16.h>

// Problem constants (Qwen3-Next linear attention defaults)
#define S_LEN   256
#define HID     2048
#define NVH     32
#define DKD     128
#define DVD     128
#define KEYDIM  512
#define VALDIM  4096
#define CONVDIM 5120
#define QKVZ_N  9216
#define EPS_F   1e-6f

typedef __attribute__((ext_vector_type(8))) short bf16x8;
typedef __attribute__((ext_vector_type(4))) float f32x4;

__device__ __forceinline__ unsigned short f2bf(float f) {
    union { float f; unsigned int i; } v; v.f = f;
    unsigned int x = v.i;
    return (unsigned short)((x + 0x7FFFu + ((x >> 16) & 1u)) >> 16); // RNE
}
__device__ __forceinline__ unsigned int pk2(float x, float y) {
    union { __hip_bfloat162 h; unsigned int u; } c;
    c.h = __float22bfloat162_rn(float2{x, y});
    return c.u;
}
__device__ __forceinline__ float4 asf4(uint4 u) {
    union { uint4 u; float4 f; } c; c.u = u; return c.f;
}
__device__ __forceinline__ uint4 cvt8_pack(float4 a, float4 b) {
    uint4 r;
    r.x = pk2(a.x, a.y); r.y = pk2(a.z, a.w);
    r.z = pk2(b.x, b.y); r.w = pk2(b.z, b.w);
    return r;
}

// ---------------------------------------------------------------------------
// Split-K MFMA GEMM: Cpart[z] = A[M,K-chunk] @ B[N,K-chunk]^T.
// A fp32 (A_F32) or bf16; B fp32 -> bf16 in staging. M fixed 256.
// Block = 256 thr = 4 waves (2x2), tile 128x128, BK=64, register prefetch.
// ---------------------------------------------------------------------------
template<bool A_F32>
__global__ __launch_bounds__(256, 2)
void gemm_tile(const void* __restrict__ Ap, const float* __restrict__ B,
               float* __restrict__ Cpart, int N, int K, int kc) {
    __shared__ __align__(16) unsigned short As[128][72];
    __shared__ __align__(16) unsigned short Bs[128][72];

    const int tid  = threadIdx.x;
    const int lane = tid & 63, wave = tid >> 6;
    const int wm = wave >> 1, wn = wave & 1;
    const int quad = lane >> 4, l16 = lane & 15;
    const int m0 = blockIdx.y * 128, n0 = blockIdx.x * 128;
    const int kbeg = blockIdx.z * kc;
    const int niter = kc >> 6;           // BK = 64

    const int lc = (tid & 7) << 3;       // col element 0,8,...,56
    const int lr = tid >> 3;             // row 0..31

    f32x4 acc[4][4];
#pragma unroll
    for (int i = 0; i < 4; i++)
#pragma unroll
        for (int j = 0; j < 4; j++) acc[i][j] = (f32x4){0.f, 0.f, 0.f, 0.f};

    uint4 qa[8], qb[8];

    auto ld_tiles = [&](int kk) {
        if constexpr (A_F32) {
            const float* a = (const float*)Ap + (size_t)(m0 + lr) * K + kk + lc;
#pragma unroll
            for (int i = 0; i < 4; i++) {
                qa[2 * i]     = *(const uint4*)(a + (size_t)(32 * i) * K);
                qa[2 * i + 1] = *(const uint4*)(a + (size_t)(32 * i) * K + 4);
            }
        } else {
            const unsigned short* a = (const unsigned short*)Ap + (size_t)(m0 + lr) * K + kk + lc;
#pragma unroll
            for (int i = 0; i < 4; i++)
                qa[i] = *(const uint4*)(a + (size_t)(32 * i) * K);
        }
        const float* b = B + (size_t)(n0 + lr) * K + kk + lc;
#pragma unroll
        for (int i = 0; i < 4; i++) {
            qb[2 * i]     = *(const uint4*)(b + (size_t)(32 * i) * K);
            qb[2 * i + 1] = *(const uint4*)(b + (size_t)(32 * i) * K + 4);
        }
    };
    auto st_tiles = [&]() {
#pragma unroll
        for (int i = 0; i < 4; i++) {
            if constexpr (A_F32)
                *(uint4*)(&As[lr + 32 * i][lc]) = cvt8_pack(asf4(qa[2 * i]), asf4(qa[2 * i + 1]));
            else
                *(uint4*)(&As[lr + 32 * i][lc]) = qa[i];
            *(uint4*)(&Bs[lr + 32 * i][lc]) = cvt8_pack(asf4(qb[2 * i]), asf4(qb[2 * i + 1]));
        }
    };

    ld_tiles(kbeg);
    st_tiles();
    __syncthreads();

    for (int it = 0; it < niter; ++it) {
        if (it + 1 < niter) ld_tiles(kbeg + (it + 1) * 64);

        bf16x8 af[2][4], bfr[2][4];
#pragma unroll
        for (int t = 0; t < 4; t++) {
#pragma unroll
            for (int ks = 0; ks < 2; ks++) {
                af[ks][t]  = *(const bf16x8*)(&As[wm * 64 + t * 16 + l16][ks * 32 + quad * 8]);
                bfr[ks][t] = *(const bf16x8*)(&Bs[wn * 64 + t * 16 + l16][ks * 32 + quad * 8]);
            }
        }
#pragma unroll
        for (int ks = 0; ks < 2; ks++)
#pragma unroll
            for (int i = 0; i < 4; i++)
#pragma unroll
                for (int j = 0; j < 4; j++)
                    acc[i][j] = __builtin_amdgcn_mfma_f32_16x16x32_bf16(af[ks][i], bfr[ks][j], acc[i][j], 0, 0, 0);

        if (it + 1 < niter) {
            __syncthreads();
            st_tiles();
            __syncthreads();
        }
    }

    float* C = Cpart + (size_t)blockIdx.z * 256 * N;
#pragma unroll
    for (int i = 0; i < 4; i++)
#pragma unroll
        for (int j = 0; j < 4; j++)
#pragma unroll
            for (int r = 0; r < 4; r++) {
                int row = m0 + wm * 64 + i * 16 + quad * 4 + r;
                int col = n0 + wn * 64 + j * 16 + l16;
                C[(size_t)row * N + col] = acc[i][j][r];
            }
}

// sum P split-K partials (each n floats apart), float4-vectorized
template<int P>
__global__ void reduce_sum(const float* __restrict__ part, float* __restrict__ out, int n) {
    int i = (blockIdx.x * 256 + threadIdx.x) * 4;
    if (i >= n) return;
    float4 s = *(const float4*)(part + i);
#pragma unroll
    for (int p = 1; p < P; p++) {
        float4 v = *(const float4*)(part + (size_t)p * n + i);
        s.x += v.x; s.y += v.y; s.z += v.z; s.w += v.w;
    }
    *(float4*)(out + i) = s;
}

// ba = hidden @ w_ba^T : [256,64]. 256 blocks x 4 waves; wave = K-chunk.
__global__ __launch_bounds__(256)
void ba_proj(const float* __restrict__ hs,
             const float* __restrict__ w_ba,
             float* __restrict__ ba) {
    int s = blockIdx.x;
    int n = threadIdx.x & 63, seg = threadIdx.x >> 6;
    const float* x = hs + (size_t)s * HID + seg * 512;
    const float* w = w_ba + (size_t)n * HID + seg * 512;
    float acc = 0.f;
#pragma unroll 4
    for (int k = 0; k < 512; k += 4) {
        float4 xv = *(const float4*)(x + k);
        float4 wv = *(const float4*)(w + k);
        acc += xv.x * wv.x + xv.y * wv.y + xv.z * wv.z + xv.w * wv.w;
    }
    __shared__ float parts[4][64];
    parts[seg][n] = acc;
    __syncthreads();
    if (threadIdx.x < 64)
        ba[s * 64 + threadIdx.x] = parts[0][threadIdx.x] + parts[1][threadIdx.x]
                                 + parts[2][threadIdx.x] + parts[3][threadIdx.x];
}

// causal depthwise conv (K=4) + silu over qkv channels (cols 0..5119 of qkvz)
__global__ void conv_silu(const float* __restrict__ qkvz,
                          const float* __restrict__ conv_w,
                          float* __restrict__ out) {
    int idx = blockIdx.x * blockDim.x + threadIdx.x;
    if (idx >= S_LEN * CONVDIM) return;
    int s = idx / CONVDIM, c = idx % CONVDIM;
    float acc = 0.f;
#pragma unroll
    for (int j = 0; j < 4; j++) {
        int t = s - 3 + j;
        if (t >= 0) acc += qkvz[(size_t)t * QKVZ_N + c] * conv_w[c * 4 + j];
    }
    out[idx] = acc / (1.f + __expf(-acc)); // silu
}

// scores[n][s][t] = (t<=s) ? (q[s]·k[t]) * DK^-0.5 * sigmoid(beta[t,n]+dt_bias[n]) : 0
// GQA: dot depends only on hk = n>>3 -> compute once, fan out over 8 v-heads.
__global__ __launch_bounds__(256)
void scores_k(const float* __restrict__ conv, const float* __restrict__ ba,
              const float* __restrict__ dt_bias, float* __restrict__ scores) {
    if (blockIdx.x > blockIdx.y) return;
    int hk = blockIdx.z;
    int s0 = blockIdx.y * 16, t0 = blockIdx.x * 16;
    __shared__ float Qs[16][132], Ks[16][132];
    int tid = threadIdx.x;
    int qoff = hk * DKD;
    int koff = KEYDIM + hk * DKD;
    for (int idx = tid; idx < 16 * 128; idx += 256) {
        int i = idx >> 7, d = idx & 127;
        Qs[i][d] = conv[(size_t)(s0 + i) * CONVDIM + qoff + d];
        Ks[i][d] = conv[(size_t)(t0 + i) * CONVDIM + koff + d];
    }
    __syncthreads();
    int tx = tid & 15, ty = tid >> 4;
    int s = s0 + ty, t = t0 + tx;
    float dot = 0.f;
    for (int d = 0; d < 128; d++) dot += Qs[ty][d] * Ks[tx][d];
    float base = (t <= s) ? dot * 0.08838834764831845f : 0.f;
#pragma unroll
    for (int v = 0; v < 8; v++) {
        int n = hk * 8 + v;
        float b = ba[t * 64 + n] + dt_bias[n];
        float bg = 1.f / (1.f + __expf(-b));
        scores[((size_t)n * 256 + s) * 256 + t] = base * bg;
    }
}

// attn[s][n][d] = sum_t scores[n][s][t] * v[t][n][d]
// One block per (16-row s-tile, head): 256 thr, 8 outputs/thread.
__global__ __launch_bounds__(256)
void attn_v(const float* __restrict__ scores, const float* __restrict__ conv,
            float* __restrict__ attn) {
    int n = blockIdx.y, s0 = blockIdx.x * 16;
    int voff = 2 * KEYDIM + n * DVD;
    __shared__ float Ss[16][17];
    __shared__ float Vs[16][132];
    int tid = threadIdx.x, sy = tid >> 4, dx = tid & 15;
    float acc[8] = {0.f, 0.f, 0.f, 0.f, 0.f, 0.f, 0.f, 0.f};
    for (int t0 = 0; t0 <= s0; t0 += 16) {
        Ss[sy][dx] = scores[((size_t)n * 256 + s0 + sy) * 256 + t0 + dx];
        const float* vp = conv + (size_t)(t0 + sy) * CONVDIM + voff + dx * 8;
        *(float4*)&Vs[sy][dx * 8]     = *(const float4*)vp;
        *(float4*)&Vs[sy][dx * 8 + 4] = *(const float4*)(vp + 4);
        __syncthreads();
#pragma unroll
        for (int j = 0; j < 16; j++) {
            float sv = Ss[sy][j];
#pragma unroll
            for (int r = 0; r < 8; r++) acc[r] += sv * Vs[j][dx + 16 * r];
        }
        __syncthreads();
    }
    float* op = attn + ((size_t)(s0 + sy) * NVH + n) * DVD;
#pragma unroll
    for (int r = 0; r < 8; r++) op[dx + 16 * r] = acc[r];
}

// gated RMSNorm over DV + silu(z) gate; emit bf16 for the final MFMA GEMM
__global__ __launch_bounds__(128)
void rmsnorm_gate(const float* __restrict__ attn, const float* __restrict__ qkvz,
                  const float* __restrict__ norm_w,
                  unsigned short* __restrict__ normed) {
    int s = blockIdx.x >> 5, n = blockIdx.x & 31;
    int d = threadIdx.x;
    float x = attn[((size_t)s * NVH + n) * DVD + d];
    float sq = x * x;
#pragma unroll
    for (int off = 32; off > 0; off >>= 1) sq += __shfl_down(sq, off, 64);
    __shared__ float parts[2];
    if ((d & 63) == 0) parts[d >> 6] = sq;
    __syncthreads();
    float ms = (parts[0] + parts[1]) * (1.f / 128.f);
    float inv = rsqrtf(ms + EPS_F);
    float z = qkvz[(size_t)s * QKVZ_N + CONVDIM + n * DVD + d];
    float sz = z / (1.f + __expf(-z));
    float v = x * inv * norm_w[d] * sz;
    normed[((size_t)s * NVH + n) * DVD + d] = f2bf(v);
}

extern "C" void kernel_launch(void* const* d_in, const int* in_sizes, int n_in,
                              void* d_out, int out_size, void* d_ws, size_t ws_size,
                              hipStream_t stream) {
    const float* hs      = (const float*)d_in[0];
    const float* w_qkvz  = (const float*)d_in[1];
    const float* w_ba    = (const float*)d_in[2];
    const float* w_out   = (const float*)d_in[3];
    const float* conv_w  = (const float*)d_in[4];
    const float* dt_bias = (const float*)d_in[5];
    const float* norm_w  = (const float*)d_in[7];

    // Workspace overlay. Front region: long-lived. Region B: scratch1 (steps
    // 1-3) shares space with normed/attn/scores (5-8) and scratch2 (8-9).
    char* ws = (char*)d_ws;
    float* qkvz = (float*)ws;  ws += (size_t)S_LEN * QKVZ_N * 4;    // 9.44 MB
    float* ba   = (float*)ws;  ws += (size_t)S_LEN * 64 * 4;
    float* conv = (float*)ws;  ws += (size_t)S_LEN * CONVDIM * 4;   // 5.24 MB
    char* regB = ws;
    float* scratch1 = (float*)regB;                                  // sk1 x 9.44 MB
    unsigned short* normed = (unsigned short*)regB;                  // 2.10 MB
    float* scratch2 = (float*)(regB + 2097152);                      // sk2 x 2.10 MB
    float* attn   = (float*)(regB + 2097152);                        // 4.19 MB
    float* scores = (float*)(regB + 2097152 + 4194304);              // 8.39 MB

    // split-K config: big needs ~52.5 MB total; fallback proven to fit.
    const bool big = ws_size >= (size_t)54 * 1024 * 1024;
    const int sk1 = big ? 4 : 2;
    const int sk2 = big ? 16 : 8;

    // 1) qkvz partials = X @ Wqkvz^T  (M=256,N=9216,K=2048)
    gemm_tile<true><<<dim3(QKVZ_N / 128, 2, sk1), 256, 0, stream>>>(hs, w_qkvz, scratch1, QKVZ_N, HID, HID / sk1);
    // 2) ba = X @ Wba^T
    ba_proj<<<S_LEN, 256, 0, stream>>>(hs, w_ba, ba);
    // 3) reduce split-K -> qkvz
    if (big) reduce_sum<4><<<(S_LEN * QKVZ_N) / 1024, 256, 0, stream>>>(scratch1, qkvz, S_LEN * QKVZ_N);
    else     reduce_sum<2><<<(S_LEN * QKVZ_N) / 1024, 256, 0, stream>>>(scratch1, qkvz, S_LEN * QKVZ_N);
    // 4) depthwise causal conv + silu
    conv_silu<<<(S_LEN * CONVDIM) / 256, 256, 0, stream>>>(qkvz, conv_w, conv);
    // 5) causal scores (dot once per k-head, fan out over 8 v-heads)
    scores_k<<<dim3(16, 16, 4), 256, 0, stream>>>(conv, ba, dt_bias, scores);
    // 6) attn = scores @ V
    attn_v<<<dim3(16, NVH), 256, 0, stream>>>(scores, conv, attn);
    // 7) gated RMSNorm -> bf16
    rmsnorm_gate<<<S_LEN * NVH, 128, 0, stream>>>(attn, qkvz, norm_w, normed);
    // 8) out partials = normed @ Wout^T (M=256,N=2048,K=4096)
    gemm_tile<false><<<dim3(HID / 128, 2, sk2), 256, 0, stream>>>(normed, w_out, scratch2, HID, VALDIM, VALDIM / sk2);
    // 9) reduce split-K -> d_out (fp32)
    if (big) reduce_sum<16><<<(S_LEN * HID) / 1024, 256, 0, stream>>>(scratch2, (float*)d_out, S_LEN * HID);
    else     reduce_sum<8><<<(S_LEN * HID) / 1024, 256, 0, stream>>>(scratch2, (float*)d_out, S_LEN * HID);
}